// Round 1
// baseline (512.556 us; speedup 1.0000x reference)
//
#include <hip/hip_runtime.h>
#include <math.h>

#define BB 2
#define HH 8
#define SS 256
#define DD 64

__global__ __launch_bounds__(256) void attn_struct_kernel(
    const float* __restrict__ query,
    const float* __restrict__ key,
    const float* __restrict__ val,
    const float* __restrict__ kst,   // [B,H,S,S,D]
    const float* __restrict__ vst,   // [B,H,S,S,D]
    const float* __restrict__ amask, // [B,S]
    float* __restrict__ out,         // [B,H,S,D]
    float* __restrict__ attn_out)    // [B,H,S,S]
{
    const int tid  = threadIdx.x;
    const int lane = tid & 63;
    const int warp = tid >> 6;
    const int blk  = blockIdx.x;            // (b*H + h)*S + q
    const int q_idx = blk & (SS - 1);
    const int bh    = blk >> 8;             // b*H + h
    const int b     = bh >> 3;

    const float* qptr  = query + (size_t)blk * DD;
    const float* kbase = key   + (size_t)bh  * SS * DD;
    const float* vbase = val   + (size_t)bh  * SS * DD;
    const float* kstp  = kst   + (size_t)blk * SS * DD;
    const float* vstp  = vst   + (size_t)blk * SS * DD;

    __shared__ float sc[SS];
    __shared__ float redm[4];
    __shared__ float reds[4];
    __shared__ float redo[4][DD];

    const int kr = tid >> 4;   // k-subrow 0..15
    const int dg = tid & 15;   // d float4-group 0..15

    const float4 qv = *(const float4*)(qptr + dg * 4);

    // ---- Phase 1: scores[k] = q . (key[k] + key_structure[q,k]) ----
    #pragma unroll 4
    for (int it = 0; it < 16; ++it) {
        const int k = it * 16 + kr;
        const float4 kv = *(const float4*)(kbase + (size_t)k * DD + dg * 4);
        const float4 sv = *(const float4*)(kstp  + (size_t)k * DD + dg * 4);
        float p = qv.x * (kv.x + sv.x) + qv.y * (kv.y + sv.y)
                + qv.z * (kv.z + sv.z) + qv.w * (kv.w + sv.w);
        // reduce over the 16 lanes of this k-row (contiguous in the wave)
        p += __shfl_xor(p, 1);
        p += __shfl_xor(p, 2);
        p += __shfl_xor(p, 4);
        p += __shfl_xor(p, 8);
        if (dg == 0) sc[k] = p;
    }
    __syncthreads();

    // ---- Phase 2: mask (per-q, pre-scale) + softmax over k ----
    const float maskv = (1.0f - amask[b * SS + q_idx]) * -100000.0f;
    float s = (sc[tid] + maskv) * 0.125f;   // 1/sqrt(64)

    float m = s;
    m = fmaxf(m, __shfl_xor(m, 1));
    m = fmaxf(m, __shfl_xor(m, 2));
    m = fmaxf(m, __shfl_xor(m, 4));
    m = fmaxf(m, __shfl_xor(m, 8));
    m = fmaxf(m, __shfl_xor(m, 16));
    m = fmaxf(m, __shfl_xor(m, 32));
    if (lane == 0) redm[warp] = m;
    __syncthreads();
    m = fmaxf(fmaxf(redm[0], redm[1]), fmaxf(redm[2], redm[3]));

    const float e = __expf(s - m);
    float t = e;
    t += __shfl_xor(t, 1);
    t += __shfl_xor(t, 2);
    t += __shfl_xor(t, 4);
    t += __shfl_xor(t, 8);
    t += __shfl_xor(t, 16);
    t += __shfl_xor(t, 32);
    if (lane == 0) reds[warp] = t;
    __syncthreads();
    const float tot = reds[0] + reds[1] + reds[2] + reds[3];
    const float a = e / tot;

    attn_out[(size_t)blk * SS + tid] = a;   // coalesced 1 KB store
    __syncthreads();                        // everyone done reading sc
    sc[tid] = a;                            // reuse sc as attn weights
    __syncthreads();

    // ---- Phase 3: out[d] = sum_k a[k] * (val[k,d] + val_structure[q,k,d]) ----
    float4 acc = make_float4(0.f, 0.f, 0.f, 0.f);
    #pragma unroll 4
    for (int it = 0; it < 16; ++it) {
        const int k = it * 16 + kr;
        const float aw = sc[k];
        const float4 vv = *(const float4*)(vbase + (size_t)k * DD + dg * 4);
        const float4 sv = *(const float4*)(vstp  + (size_t)k * DD + dg * 4);
        acc.x += aw * (vv.x + sv.x);
        acc.y += aw * (vv.y + sv.y);
        acc.z += aw * (vv.z + sv.z);
        acc.w += aw * (vv.w + sv.w);
    }
    // reduce across the 4 k-groups sharing this dg within the wave
    acc.x += __shfl_xor(acc.x, 16); acc.y += __shfl_xor(acc.y, 16);
    acc.z += __shfl_xor(acc.z, 16); acc.w += __shfl_xor(acc.w, 16);
    acc.x += __shfl_xor(acc.x, 32); acc.y += __shfl_xor(acc.y, 32);
    acc.z += __shfl_xor(acc.z, 32); acc.w += __shfl_xor(acc.w, 32);
    if (lane < 16) {
        redo[warp][lane * 4 + 0] = acc.x;
        redo[warp][lane * 4 + 1] = acc.y;
        redo[warp][lane * 4 + 2] = acc.z;
        redo[warp][lane * 4 + 3] = acc.w;
    }
    __syncthreads();
    if (tid < DD) {
        out[(size_t)blk * DD + tid] =
            redo[0][tid] + redo[1][tid] + redo[2][tid] + redo[3][tid];
    }
}

extern "C" void kernel_launch(void* const* d_in, const int* in_sizes, int n_in,
                              void* d_out, int out_size, void* d_ws, size_t ws_size,
                              hipStream_t stream) {
    const float* query = (const float*)d_in[0];
    const float* key   = (const float*)d_in[1];
    const float* val   = (const float*)d_in[2];
    const float* kst   = (const float*)d_in[3];
    const float* vst   = (const float*)d_in[4];
    const float* amask = (const float*)d_in[5];

    float* out  = (float*)d_out;
    float* attn = out + (size_t)BB * HH * SS * DD;

    attn_struct_kernel<<<BB * HH * SS, 256, 0, stream>>>(
        query, key, val, kst, vst, amask, out, attn);
}

// Round 3
// 499.418 us; speedup vs baseline: 1.0263x; 1.0263x over previous
//
#include <hip/hip_runtime.h>
#include <math.h>

#define BB 2
#define HH 8
#define SS 256
#define DD 64
#define PAD 17   // 256x17 floats: stride-17 breaks all power-of-2 bank patterns

typedef float vfloat4 __attribute__((ext_vector_type(4)));

__global__ __launch_bounds__(256, 4) void attn_struct_kernel(
    const float* __restrict__ query,
    const float* __restrict__ key,
    const float* __restrict__ val,
    const float* __restrict__ kst,   // [B,H,S,S,D]
    const float* __restrict__ vst,   // [B,H,S,S,D]
    const float* __restrict__ amask, // [B,S]
    float* __restrict__ out,         // [B,H,S,D]
    float* __restrict__ attn_out)    // [B,H,S,S]
{
    const int tid  = threadIdx.x;
    const int lane = tid & 63;
    const int warp = tid >> 6;
    const int blk  = blockIdx.x;            // (b*H + h)*S + q
    const int q_idx = blk & (SS - 1);
    const int bh    = blk >> 8;             // b*H + h
    const int b     = bh >> 3;

    const float* qptr  = query + (size_t)blk * DD;
    const float* kbase = key   + (size_t)bh  * SS * DD;
    const float* vbase = val   + (size_t)bh  * SS * DD;
    const float* kstp  = kst   + (size_t)blk * SS * DD;
    const float* vstp  = vst   + (size_t)blk * SS * DD;

    __shared__ float part[SS * PAD];  // 17408 B: per-(k, d-group) partial dots
    __shared__ float sc[SS];
    __shared__ float redm[4];
    __shared__ float reds[4];
    __shared__ float redo[4][DD];

    const int kr = tid >> 4;   // k-subrow 0..15
    const int dg = tid & 15;   // d float4-group 0..15

    const vfloat4 qv = *(const vfloat4*)(qptr + dg * 4);

    // ---- Phase 1: 16 INDEPENDENT partials; no cross-lane ops in the loop ----
    float p[16];
    #pragma unroll
    for (int it = 0; it < 16; ++it) {
        const int k = it * 16 + kr;
        const vfloat4 kv = *(const vfloat4*)(kbase + (size_t)k * DD + dg * 4);
        const vfloat4 sv = __builtin_nontemporal_load(
            (const vfloat4*)(kstp + (size_t)k * DD + dg * 4));
        p[it] = qv.x * (kv.x + sv.x) + qv.y * (kv.y + sv.y)
              + qv.z * (kv.z + sv.z) + qv.w * (kv.w + sv.w);
    }
    #pragma unroll
    for (int it = 0; it < 16; ++it) {
        part[(it * 16 + kr) * PAD + dg] = p[it];
    }
    __syncthreads();

    // ---- Phase 2: per-k reduction (stride-17 = 2 lanes/bank, free) + softmax ----
    float s = 0.f;
    #pragma unroll
    for (int j = 0; j < 16; ++j) s += part[tid * PAD + j];

    const float maskv = (1.0f - amask[b * SS + q_idx]) * -100000.0f;
    s = (s + maskv) * 0.125f;   // 1/sqrt(64)

    float m = s;
    m = fmaxf(m, __shfl_xor(m, 1));
    m = fmaxf(m, __shfl_xor(m, 2));
    m = fmaxf(m, __shfl_xor(m, 4));
    m = fmaxf(m, __shfl_xor(m, 8));
    m = fmaxf(m, __shfl_xor(m, 16));
    m = fmaxf(m, __shfl_xor(m, 32));
    if (lane == 0) redm[warp] = m;
    __syncthreads();
    m = fmaxf(fmaxf(redm[0], redm[1]), fmaxf(redm[2], redm[3]));

    const float e = __expf(s - m);
    float t = e;
    t += __shfl_xor(t, 1);
    t += __shfl_xor(t, 2);
    t += __shfl_xor(t, 4);
    t += __shfl_xor(t, 8);
    t += __shfl_xor(t, 16);
    t += __shfl_xor(t, 32);
    if (lane == 0) reds[warp] = t;
    __syncthreads();
    const float tot = reds[0] + reds[1] + reds[2] + reds[3];
    const float a = e / tot;

    attn_out[(size_t)blk * SS + tid] = a;   // coalesced 1 KB store
    sc[tid] = a;
    __syncthreads();

    // ---- Phase 3: out[d] = sum_k a[k]*(val[k,d]+vst[q,k,d]); fully unrolled ----
    vfloat4 acc = (vfloat4)(0.f);
    #pragma unroll
    for (int it = 0; it < 16; ++it) {
        const int k = it * 16 + kr;
        const float aw = sc[k];              // LDS broadcast (same addr per 16 lanes)
        const vfloat4 vv = *(const vfloat4*)(vbase + (size_t)k * DD + dg * 4);
        const vfloat4 sv = __builtin_nontemporal_load(
            (const vfloat4*)(vstp + (size_t)k * DD + dg * 4));
        acc.x += aw * (vv.x + sv.x);
        acc.y += aw * (vv.y + sv.y);
        acc.z += aw * (vv.z + sv.z);
        acc.w += aw * (vv.w + sv.w);
    }
    // reduce across the 4 kr-groups within the wave (2 shuffles, once)
    acc.x += __shfl_xor(acc.x, 16); acc.y += __shfl_xor(acc.y, 16);
    acc.z += __shfl_xor(acc.z, 16); acc.w += __shfl_xor(acc.w, 16);
    acc.x += __shfl_xor(acc.x, 32); acc.y += __shfl_xor(acc.y, 32);
    acc.z += __shfl_xor(acc.z, 32); acc.w += __shfl_xor(acc.w, 32);
    if (lane < 16) {
        redo[warp][lane * 4 + 0] = acc.x;
        redo[warp][lane * 4 + 1] = acc.y;
        redo[warp][lane * 4 + 2] = acc.z;
        redo[warp][lane * 4 + 3] = acc.w;
    }
    __syncthreads();
    if (tid < DD) {
        out[(size_t)blk * DD + tid] =
            redo[0][tid] + redo[1][tid] + redo[2][tid] + redo[3][tid];
    }
}

extern "C" void kernel_launch(void* const* d_in, const int* in_sizes, int n_in,
                              void* d_out, int out_size, void* d_ws, size_t ws_size,
                              hipStream_t stream) {
    const float* query = (const float*)d_in[0];
    const float* key   = (const float*)d_in[1];
    const float* val   = (const float*)d_in[2];
    const float* kst   = (const float*)d_in[3];
    const float* vst   = (const float*)d_in[4];
    const float* amask = (const float*)d_in[5];

    float* out  = (float*)d_out;
    float* attn = out + (size_t)BB * HH * SS * DD;

    attn_struct_kernel<<<BB * HH * SS, 256, 0, stream>>>(
        query, key, val, kst, vst, amask, out, attn);
}